// Round 12
// baseline (258.962 us; speedup 1.0000x reference)
//
#include <hip/hip_runtime.h>
#include <cstdint>

#define BB 16
#define LL 32768
#define NC 512               // chunks per (b,dir)
#define NSPAN 32             // NC/16 spans per (b,dir)
#define SPLEN 16             // chunks per span

// ---- weight block layout (floats) in ws[0..4096B) ----
#define WD_SZ 256            // per-direction block
#define XPW 0                // x_proj rows [33][4]
#define CVW 132              // conv_w [4][4]
#define CVB 148              // conv_b [4]
#define DTW 152              // dt_proj_w [4]
#define DTB 156              // dt_proj_b [4]
#define AW  160              // A = -exp(A_log)*log2(e) [4][16]  (pre-scaled for exp2)
#define DW  224              // D [4]
#define G_INPROJ 512         // in_proj [8][2]
#define G_NORMW 528
#define G_OUTP 530           // out_proj [2][4]
#define G_NORMF 538
#define FLG 1000             // 1.0f if inputs/outputs fp32, 0.0f if bf16

// ---- ws byte offsets (~68 MiB) ----
#define PQ_OFF 4096
#define PQ_BYTES ((size_t)BB*2*NC*64*8)            // 8.39 MB  per-chunk (P,Q)
#define SP_OFF (PQ_OFF + PQ_BYTES)
#define SP_BYTES ((size_t)BB*2*NSPAN*64*8)         // 0.52 MB  span tables
#define SG_OFF (SP_OFF + SP_BYTES)
#define SG_BYTES ((size_t)BB*NC*2*64*4*4)          // 16.8 MB  s_t[d] fp32 [cd][t][d]
#define CG_OFF (SG_OFF + SG_BYTES)
#define CG_BYTES ((size_t)BB*NC*2*64*16*2)         // 33.6 MB  C bf16 [cd][t][n]
#define YB_OFF (CG_OFF + CG_BYTES)
#define YB_BYTES ((size_t)BB*NC*64*4*4)            // 8.39 MB  ybase fp32 [g][t][d]

#define LOG2E 1.4426950408889634f

__device__ __forceinline__ float bf2f(unsigned short u){ return __uint_as_float(((unsigned int)u)<<16); }
__device__ __forceinline__ float blo(unsigned int u){ return __uint_as_float(u<<16); }
__device__ __forceinline__ float bhi(unsigned int u){ return __uint_as_float(u & 0xffff0000u); }

// HW packed f32->bf16 (RNE). 1 VALU inst.
__device__ __forceinline__ unsigned int cvtpk(float lo, float hi){
  unsigned int r;
  asm("v_cvt_pk_bf16_f32 %0, %1, %2" : "=v"(r) : "v"(lo), "v"(hi));
  return r;
}
__device__ __forceinline__ unsigned short cvt1(float x){
  return (unsigned short)cvtpk(x, x);
}

__device__ __forceinline__ float siluf(float x){ return x / (1.f + __expf(-x)); }
__device__ __forceinline__ float softplusf_(float x){ return fmaxf(x,0.f) + log1pf(__expf(-fabsf(x))); }

// raw v_exp_f32 (exp2). A is pre-scaled by log2(e) so no extra mul.
__device__ __forceinline__ float exp2fast(float x){
#if __has_builtin(__builtin_amdgcn_exp2f)
  return __builtin_amdgcn_exp2f(x);
#else
  float r; asm("v_exp_f32 %0, %1\ns_nop 0" : "=v"(r) : "v"(x)); return r;
#endif
}

// sum over the 16-lane DPP row (lanes n=0..15 of each d-group).
__device__ __forceinline__ float rowsum16(float x){
  asm("s_nop 1\n\t"
      "v_add_f32_dpp %0, %0, %0 row_ror:1 row_mask:0xf bank_mask:0xf\n\t"
      "s_nop 1\n\t"
      "v_add_f32_dpp %0, %0, %0 row_ror:2 row_mask:0xf bank_mask:0xf\n\t"
      "s_nop 1\n\t"
      "v_add_f32_dpp %0, %0, %0 row_ror:4 row_mask:0xf bank_mask:0xf\n\t"
      "s_nop 1\n\t"
      "v_add_f32_dpp %0, %0, %0 row_ror:8 row_mask:0xf bank_mask:0xf"
      : "+v"(x));
  return x;
}

// wave64 inclusive prefix sum (DPP scan).
__device__ __forceinline__ float wavescan_incl(float x){
  union { float f; int i; } a, t;
  a.f = x;
  t.i = __builtin_amdgcn_update_dpp(0, a.i, 0x111, 0xf, 0xf, true); a.f += t.f; // row_shr:1
  t.i = __builtin_amdgcn_update_dpp(0, a.i, 0x112, 0xf, 0xf, true); a.f += t.f; // row_shr:2
  t.i = __builtin_amdgcn_update_dpp(0, a.i, 0x114, 0xf, 0xf, true); a.f += t.f; // row_shr:4
  t.i = __builtin_amdgcn_update_dpp(0, a.i, 0x118, 0xf, 0xf, true); a.f += t.f; // row_shr:8
  t.i = __builtin_amdgcn_update_dpp(0, a.i, 0x142, 0xa, 0xf, true); a.f += t.f; // row_bcast:15
  t.i = __builtin_amdgcn_update_dpp(0, a.i, 0x143, 0xc, 0xf, true); a.f += t.f; // row_bcast:31
  return a.f;
}
__device__ __forceinline__ float readlane63(float x){
  union { float f; int i; } a; a.f = x;
  return __uint_as_float((unsigned)__builtin_amdgcn_readlane(a.i, 63));
}

__device__ __forceinline__ float ldw(const void* p, int i, int isf){
  return isf ? ((const float*)p)[i] : bf2f(((const unsigned short*)p)[i]);
}
__device__ __forceinline__ float2 hid2(const void* hid, int isf, int b, int t){
  if (isf){
    const float* p = (const float*)hid;
    return make_float2(p[(size_t)b*2*LL + t], p[(size_t)b*2*LL + LL + t]);
  }
  const unsigned short* p = (const unsigned short*)hid;
  return make_float2(bf2f(p[(size_t)b*2*LL + t]), bf2f(p[(size_t)b*2*LL + LL + t]));
}
__device__ __forceinline__ float4 xrow(const void* __restrict__ hid, int isf,
                                       const float* __restrict__ W, int b, int t){
  float2 h = hid2(hid, isf, b, t);
  float ms = rsqrtf(0.5f*(h.x*h.x + h.y*h.y) + 1e-5f);
  float v0 = h.x*ms*W[G_NORMW], v1 = h.y*ms*W[G_NORMW+1];
  float4 x;
  x.x = W[G_INPROJ+0]*v0 + W[G_INPROJ+1]*v1;
  x.y = W[G_INPROJ+2]*v0 + W[G_INPROJ+3]*v1;
  x.z = W[G_INPROJ+4]*v0 + W[G_INPROJ+5]*v1;
  x.w = W[G_INPROJ+6]*v0 + W[G_INPROJ+7]*v1;
  return x;
}

// ---------------- kernel 0: weight prep ----------------
__global__ void k_prep(const void* __restrict__ normw, const void* __restrict__ inpj,
    const void* __restrict__ cwf, const void* __restrict__ cbf,
    const void* __restrict__ xpf, const void* __restrict__ dwf,
    const void* __restrict__ dbf, const void* __restrict__ alf,
    const void* __restrict__ ddf,
    const void* __restrict__ cwb, const void* __restrict__ cbb,
    const void* __restrict__ xpb, const void* __restrict__ dwb,
    const void* __restrict__ dbb, const void* __restrict__ alb,
    const void* __restrict__ ddb,
    const void* __restrict__ outp, const void* __restrict__ nfw,
    float* __restrict__ W)
{
  const int isf = (((const unsigned int*)ddf)[0] == 0x3F800000u) ? 1 : 0;
  int t = threadIdx.x;
  for (int i=t;i<132;i+=256){ W[XPW+i]=ldw(xpf,i,isf); W[WD_SZ+XPW+i]=ldw(xpb,i,isf); }
  for (int i=t;i<16;i+=256){ W[CVW+i]=ldw(cwf,i,isf); W[WD_SZ+CVW+i]=ldw(cwb,i,isf); W[G_INPROJ+i]=ldw(inpj,i,isf); }
  for (int i=t;i<4;i+=256){
    W[CVB+i]=ldw(cbf,i,isf); W[WD_SZ+CVB+i]=ldw(cbb,i,isf);
    W[DTW+i]=ldw(dwf,i,isf); W[WD_SZ+DTW+i]=ldw(dwb,i,isf);
    W[DTB+i]=ldw(dbf,i,isf); W[WD_SZ+DTB+i]=ldw(dbb,i,isf);
    W[DW+i] =ldw(ddf,i,isf); W[WD_SZ+DW+i] =ldw(ddb,i,isf);
  }
  for (int i=t;i<64;i+=256){
    W[AW+i]       = -__expf(ldw(alf,i,isf)) * LOG2E;
    W[WD_SZ+AW+i] = -__expf(ldw(alb,i,isf)) * LOG2E;
  }
  for (int i=t;i<8;i+=256) W[G_OUTP+i]=ldw(outp,i,isf);
  for (int i=t;i<2;i+=256){ W[G_NORMW+i]=ldw(normw,i,isf); W[G_NORMF+i]=ldw(nfw,i,isf); }
  if (t==0) W[FLG] = (float)isf;
}

// ---- per-direction local scan (returns local h). Fully unrolled so all
// LDS accesses become base + compile-time immediate (no per-iter addr math).
template<int DR>
__device__ __forceinline__ float scan_local(const float (* __restrict__ dtPd)[68],
    const float (* __restrict__ dtud)[68],
    const unsigned int (* __restrict__ bcd)[68],
    float (* __restrict__ ySd)[68],
    float Ax, int d, int n)
{
  float h = 0.f;
  #pragma unroll
  for (int j4=0; j4<16; j4++){
    const int t0 = DR ? 60-4*j4 : 4*j4;
    float4  d4 = *(const float4*)&dtPd[d][t0];
    float4  u4 = *(const float4*)&dtud[d][t0];
    uint4   c4 = *(const uint4*)&bcd[n][t0];
    float da[4]={d4.x,d4.y,d4.z,d4.w};
    float ua[4]={u4.x,u4.y,u4.z,u4.w};
    unsigned int ca[4]={c4.x,c4.y,c4.z,c4.w};
    float s[4];
    #pragma unroll
    for (int jr=0; jr<4; jr++){
      const int k  = DR ? 3-jr : jr;         // bwd consumes t descending
      float e = exp2fast(Ax*da[k]);
      h = fmaf(e, h, ua[k]*blo(ca[k]));
      s[k] = rowsum16(h*bhi(ca[k]));
    }
    if (n == 0) *(float4*)&ySd[d][t0] = make_float4(s[0],s[1],s[2],s[3]);
  }
  return h;
}

// ---------------- kernel 1: per-chunk local scan, dir per wave ----------------
__global__ __launch_bounds__(128, 4) void k_chunk2(const void* __restrict__ hid,
    const float* __restrict__ W, float2* __restrict__ PQ,
    float* __restrict__ sG, unsigned int* __restrict__ Cg,
    float4* __restrict__ YB)
{
  // xb (1120B, dead after preamble) overlaps yS (2176B, written during scan)
  __shared__ __align__(16) char smx[2176];
  __shared__ __align__(16) float dtP[2][4][68];            // 2176
  __shared__ __align__(16) float dtuP[2][4][68];           // 2176 fp32 dt*u
  __shared__ __align__(16) unsigned int BCp[2][16][68];    // 8704 (B | C<<16) bf16
  __shared__ __align__(16) float uD[2][256];               // 2048 u*D
  __shared__ float sTot[2][4];
  float4* xb = (float4*)smx;
  float (*yS)[4][68] = (float (*)[4][68])smx;

  const int tid  = threadIdx.x;
  const int wid  = tid >> 6;         // 0=fwd wave, 1=bwd wave
  const int lane = tid & 63;
  const int gid  = blockIdx.x;       // (b,c)
  const int c    = gid & (NC-1);
  const int b    = gid >> 9;
  const int isf  = (int)W[FLG];
  const size_t cd = (size_t)gid*2 + wid;

  // xb staging split over ALL 128 threads: xb[e] <-> t = c*64 - 3 + e, e in [0,70)
  if (tid < 70){
    int t2 = c*64 - 3 + tid;
    float4 v = make_float4(0.f,0.f,0.f,0.f);
    if (t2 >= 0 && t2 < LL) v = xrow(hid, isf, W, b, t2);
    xb[tid] = v;
  }
  __syncthreads();
  {
    const float* Wd = W + wid*WD_SZ;
    float4 a0,a1,a2,a3;
    if (wid == 0){ a0=xb[lane];   a1=xb[lane+1]; a2=xb[lane+2]; a3=xb[lane+3]; }
    else         { a0=xb[lane+6]; a1=xb[lane+5]; a2=xb[lane+4]; a3=xb[lane+3]; }
    float u[4];
    u[0] = siluf(Wd[CVB+0] + Wd[CVW+ 0]*a0.x + Wd[CVW+ 1]*a1.x + Wd[CVW+ 2]*a2.x + Wd[CVW+ 3]*a3.x);
    u[1] = siluf(Wd[CVB+1] + Wd[CVW+ 4]*a0.y + Wd[CVW+ 5]*a1.y + Wd[CVW+ 6]*a2.y + Wd[CVW+ 7]*a3.y);
    u[2] = siluf(Wd[CVB+2] + Wd[CVW+ 8]*a0.z + Wd[CVW+ 9]*a1.z + Wd[CVW+10]*a2.z + Wd[CVW+11]*a3.z);
    u[3] = siluf(Wd[CVB+3] + Wd[CVW+12]*a0.w + Wd[CVW+13]*a1.w + Wd[CVW+14]*a2.w + Wd[CVW+15]*a3.w);
    float dtr = Wd[XPW+0]*u[0] + Wd[XPW+1]*u[1] + Wd[XPW+2]*u[2] + Wd[XPW+3]*u[3];
    float4 ud4;
    #pragma unroll
    for (int d2=0; d2<4; d2++){
      float dt = softplusf_(fmaf(Wd[DTW+d2], dtr, Wd[DTB+d2]));
      dtP[wid][d2][lane]  = dt;
      dtuP[wid][d2][lane] = dt*u[d2];
      ((float*)&ud4)[d2] = u[d2]*Wd[DW+d2];
    }
    *(float4*)&uD[wid][lane*4] = ud4;
    float Cl[16];
    #pragma unroll
    for (int n=0; n<16; n++){
      float Bn = Wd[XPW+(1+n)*4+0]*u[0] + Wd[XPW+(1+n)*4+1]*u[1]
               + Wd[XPW+(1+n)*4+2]*u[2] + Wd[XPW+(1+n)*4+3]*u[3];
      float Cn = Wd[XPW+(17+n)*4+0]*u[0] + Wd[XPW+(17+n)*4+1]*u[1]
               + Wd[XPW+(17+n)*4+2]*u[2] + Wd[XPW+(17+n)*4+3]*u[3];
      BCp[wid][n][lane] = cvtpk(Bn, Cn);
      Cl[n] = Cn;
    }
    // store C row for k_final: [cd][t][n] bf16, 32B per lane
    unsigned int cp[8];
    #pragma unroll
    for (int q=0;q<8;q++) cp[q] = cvtpk(Cl[2*q], Cl[2*q+1]);
    uint4* cgw = (uint4*)(Cg + cd*512);
    cgw[lane*2+0] = *(uint4*)&cp[0];
    cgw[lane*2+1] = *(uint4*)&cp[4];
  }
  __syncthreads();   // also protects xb->yS union

  // cumulative dt (prefix-incl for fwd, suffix-incl for bwd), lane = t
  {
    float sv[4], tt[4];
    #pragma unroll
    for (int d2=0; d2<4; d2++){
      float v = dtP[wid][d2][lane];
      float x = wavescan_incl(v);
      float tot = readlane63(x);
      if (wid) x = tot - x + v;        // suffix-inclusive
      sv[d2] = x; tt[d2] = tot;
    }
    *(float4*)(sG + cd*256 + lane*4) = make_float4(sv[0],sv[1],sv[2],sv[3]);
    if (lane == 0){ sTot[wid][0]=tt[0]; sTot[wid][1]=tt[1]; sTot[wid][2]=tt[2]; sTot[wid][3]=tt[3]; }
  }

  const int d = lane>>4, n = lane&15;
  const float Ax = W[wid*WD_SZ + AW + d*16 + n];
  float h;
  size_t idx;
  if (wid == 0){
    h   = scan_local<0>(dtP[0], dtuP[0], BCp[0], yS[0], Ax, d, n);
    idx = ((size_t)(b*2+0)*NC + c);
  } else {
    h   = scan_local<1>(dtP[1], dtuP[1], BCp[1], yS[1], Ax, d, n);
    idx = ((size_t)(b*2+1)*NC + (NC-1-c));
  }
  float P = exp2fast(Ax * sTot[wid][d]);   // = prod of per-step decays
  PQ[idx*64 + lane] = make_float2(P, h);
  __syncthreads();

  // ybase = y_loc_f + y_loc_b + uD_f + uD_b   (fp32, [t][d] float4)
  if (wid == 0){
    float4 v;
    v.x = yS[0][0][lane] + yS[1][0][lane] + uD[0][lane*4+0] + uD[1][lane*4+0];
    v.y = yS[0][1][lane] + yS[1][1][lane] + uD[0][lane*4+1] + uD[1][lane*4+1];
    v.z = yS[0][2][lane] + yS[1][2][lane] + uD[0][lane*4+2] + uD[1][lane*4+2];
    v.w = yS[0][3][lane] + yS[1][3][lane] + uD[0][lane*4+3] + uD[1][lane*4+3];
    YB[(size_t)gid*64 + lane] = v;
  }
}

// ---------------- kernel 2: span tables (16-chunk composition) ----------------
__global__ __launch_bounds__(64) void k_spans(const float2* __restrict__ PQ,
                                              float2* __restrict__ SP)
{
  const int blk  = blockIdx.x;           // bd*NSPAN + span
  const int lane = threadIdx.x;
  const int bd   = blk >> 5, span = blk & (NSPAN-1);
  const float2* p = PQ + ((size_t)bd*NC + span*SPLEN)*64 + lane;
  float2 v[SPLEN];
  #pragma unroll
  for (int k=0;k<SPLEN;k++) v[k] = p[k*64];
  float A = 1.f, Bc = 0.f;
  #pragma unroll
  for (int k=0;k<SPLEN;k++){ A *= v[k].x; Bc = fmaf(v[k].x, Bc, v[k].y); }
  SP[((size_t)bd*NSPAN + span)*64 + lane] = make_float2(A,Bc);
}

// compose entry state for (bd, position p): s full spans + wn chunk entries
__device__ __forceinline__ float compose_h0(const float2* __restrict__ PQ,
    const float2* __restrict__ SP, int bd, int p, int lane)
{
  const int s  = p >> 4, wn = p & 15;
  const float2* SPb = SP + (size_t)bd*NSPAN*64 + lane;
  const float2* PQb = PQ + ((size_t)bd*NC + (p & ~15))*64 + lane;
  float h = 0.f;
  #pragma unroll
  for (int jg=0; jg<4; jg++){
    if (jg*8 < s){                         // wave-uniform group skip
      float2 v[8];
      #pragma unroll
      for (int j=0;j<8;j++){ int jj = jg*8+j; v[j] = SPb[(size_t)(jj<s?jj:0)*64]; }
      #pragma unroll
      for (int j=0;j<8;j++){ int jj = jg*8+j; if (jj<s) h = fmaf(v[j].x, h, v[j].y); }
    }
  }
  #pragma unroll
  for (int jg=0; jg<2; jg++){
    if (jg*8 < wn){
      float2 v[8];
      #pragma unroll
      for (int j=0;j<8;j++){ int jj = jg*8+j; v[j] = PQb[(size_t)(jj<wn?jj:0)*64]; }
      #pragma unroll
      for (int j=0;j<8;j++){ int jj = jg*8+j; if (jj<wn) h = fmaf(v[j].x, h, v[j].y); }
    }
  }
  return h;
}

// ---- one direction's correction: compose h0, publish to LDS slice, dot ----
__device__ __forceinline__ void corr_dir(const float2* __restrict__ PQ,
    const float2* __restrict__ SP, const float* __restrict__ sG,
    const unsigned int* __restrict__ Cg, const float* __restrict__ Wa,
    float (* __restrict__ h0s)[64], int w, int lane,
    int bd, int p, size_t cdd, float* corr)
{
  // issue this dir's loads first (in flight during the compose chain)
  float4 s4 = *(const float4*)(sG + cdd*256 + lane*4);
  uint4 c8a = ((const uint4*)(Cg + cdd*512))[lane*2+0];
  uint4 c8b = ((const uint4*)(Cg + cdd*512))[lane*2+1];

  float h = compose_h0(PQ, SP, bd, p, lane);
  h0s[w][lane] = h;        // same-wave write->read, lgkmcnt ordering

  unsigned int u8[8] = {c8a.x,c8a.y,c8a.z,c8a.w,c8b.x,c8b.y,c8b.z,c8b.w};
  #pragma unroll
  for (int d2=0; d2<4; d2++){
    float sd = ((const float*)&s4)[d2];
    float acc = corr[d2];
    #pragma unroll
    for (int q=0;q<4;q++){
      float4 a4 = *(const float4*)(Wa + d2*16 + q*4);
      float4 h4 = *(const float4*)&h0s[w][d2*16 + q*4];
      unsigned int p0 = u8[d2*4 + 0 + (q>>1)*0];  // placeholder (see below)
      (void)p0;
      unsigned int w0 = u8[2*q], w1 = u8[2*q+1];
      // NOTE: u8[2q],u8[2q+1] hold C[8q..8q+3] pairs? No: u8[k] = C[2k],C[2k+1].
      // quarter q covers n = 4q..4q+3 -> words u8[2q] (n=4q,4q+1), u8[2q+1].
      acc = fmaf(exp2fast(a4.x*sd), blo(w0)*h4.x, acc);
      acc = fmaf(exp2fast(a4.y*sd), bhi(w0)*h4.y, acc);
      acc = fmaf(exp2fast(a4.z*sd), blo(w1)*h4.z, acc);
      acc = fmaf(exp2fast(a4.w*sd), bhi(w1)*h4.w, acc);
    }
    corr[d2] = acc;
  }
}

// ---------------- kernel 3: one wave per chunk, dirs SEQUENTIAL ----------------
// 2048 blocks x 256 thr. Sequential-dir processing halves live VGPR state
// (one dir's s/C/compose regs at a time) -> target <=64 VGPR -> 8 waves/EU.
// k_final is LLC-BW/latency-bound; 2x occupancy = 2x outstanding misses.
__global__ __launch_bounds__(256, 8) void k_final(const void* __restrict__ hid,
    const float* __restrict__ W, const float2* __restrict__ PQ,
    const float2* __restrict__ SP, const float* __restrict__ sG,
    const unsigned int* __restrict__ Cg, const float4* __restrict__ YB,
    void* __restrict__ out)
{
  __shared__ float h0s[4][64];             // one slice per wave, reused per dir
  const int lane = threadIdx.x & 63;
  const int w    = threadIdx.x >> 6;
  const int unit = blockIdx.x*4 + w;       // b*NC + c
  const int b    = unit >> 9;
  const int c    = unit & (NC-1);
  const int isf  = (int)W[FLG];
  const int tg   = c*64 + lane;

  // loads needed by the epilogue (issued early, live across both dirs)
  float4 yb = YB[(size_t)unit*64 + lane];
  float2 r = hid2(hid, isf, b, tg);

  float corr[4] = {0.f,0.f,0.f,0.f};
  // fwd
  corr_dir(PQ, SP, sG, Cg, W + AW,        h0s, w, lane, b*2+0, c,      (size_t)unit*2+0, corr);
  // bwd (reuses h0s slice; same-wave program order guarantees the fwd reads
  // completed before the bwd write)
  corr_dir(PQ, SP, sG, Cg, W + WD_SZ+AW,  h0s, w, lane, b*2+1, NC-1-c, (size_t)unit*2+1, corr);

  // epilogue (lane = t)
  {
    float ms0 = rsqrtf(0.5f*(r.x*r.x + r.y*r.y) + 1e-5f);
    float v0 = r.x*ms0*W[G_NORMW], v1 = r.y*ms0*W[G_NORMW+1];
    float z0 = siluf(W[G_INPROJ+ 8]*v0 + W[G_INPROJ+ 9]*v1);
    float z1 = siluf(W[G_INPROJ+10]*v0 + W[G_INPROJ+11]*v1);
    float z2 = siluf(W[G_INPROJ+12]*v0 + W[G_INPROJ+13]*v1);
    float z3 = siluf(W[G_INPROJ+14]*v0 + W[G_INPROJ+15]*v1);

    float y0 = (yb.x + corr[0]) * z0;
    float y1 = (yb.y + corr[1]) * z1;
    float y2 = (yb.z + corr[2]) * z2;
    float y3 = (yb.w + corr[3]) * z3;
    float o0 = W[G_OUTP+0]*y0 + W[G_OUTP+1]*y1 + W[G_OUTP+2]*y2 + W[G_OUTP+3]*y3;
    float o1 = W[G_OUTP+4]*y0 + W[G_OUTP+5]*y1 + W[G_OUTP+6]*y2 + W[G_OUTP+7]*y3;
    o0 += r.x;
    o1 += r.y;
    float ms = rsqrtf(0.5f*(o0*o0 + o1*o1) + 1e-5f);
    float e0 = o0*ms*W[G_NORMF], e1 = o1*ms*W[G_NORMF+1];
    size_t i0 = (size_t)b*2*LL + tg, i1 = i0 + LL;
    if (isf){
      ((float*)out)[i0] = e0;
      ((float*)out)[i1] = e1;
    } else {
      ((unsigned short*)out)[i0] = cvt1(e0);
      ((unsigned short*)out)[i1] = cvt1(e1);
    }
  }
}

extern "C" void kernel_launch(void* const* d_in, const int* in_sizes, int n_in,
                              void* d_out, int out_size, void* d_ws, size_t ws_size,
                              hipStream_t stream)
{
  (void)in_sizes; (void)n_in; (void)out_size; (void)ws_size;
  const void* hid   = d_in[0];
  const void* normw = d_in[1];
  const void* inpj  = d_in[2];
  const void* cwf   = d_in[3];
  const void* cbf   = d_in[4];
  const void* xpf   = d_in[5];
  const void* dwf   = d_in[6];
  const void* dbf   = d_in[7];
  const void* alf   = d_in[8];
  const void* ddf   = d_in[9];
  const void* cwb   = d_in[10];
  const void* cbb   = d_in[11];
  const void* xpb   = d_in[12];
  const void* dwb   = d_in[13];
  const void* dbb   = d_in[14];
  const void* alb   = d_in[15];
  const void* ddb   = d_in[16];
  const void* outp  = d_in[17];
  const void* nfw   = d_in[18];

  float* W            = (float*)d_ws;
  float2* PQ          = (float2*)((char*)d_ws + PQ_OFF);
  float2* SPt         = (float2*)((char*)d_ws + SP_OFF);
  float* sG           = (float*)((char*)d_ws + SG_OFF);
  unsigned int* Cg    = (unsigned int*)((char*)d_ws + CG_OFF);
  float4* YB          = (float4*)((char*)d_ws + YB_OFF);

  k_prep<<<1,256,0,stream>>>(normw, inpj, cwf, cbf, xpf, dwf, dbf, alf, ddf,
                             cwb, cbb, xpb, dwb, dbb, alb, ddb, outp, nfw, W);
  k_chunk2<<<BB*NC, 128, 0, stream>>>(hid, W, PQ, sG, Cg, YB);
  k_spans<<<BB*2*NSPAN, 64, 0, stream>>>(PQ, SPt);
  k_final<<<BB*NC/4, 256, 0, stream>>>(hid, W, PQ, SPt, sG, Cg, YB, d_out);
}

// Round 13
// 170.197 us; speedup vs baseline: 1.5215x; 1.5215x over previous
//
#include <hip/hip_runtime.h>
#include <cstdint>

#define BB 16
#define LL 32768
#define NC 512               // chunks per (b,dir)
#define NSPAN 32             // NC/16 spans per (b,dir)
#define SPLEN 16             // chunks per span

// ---- weight block layout (floats) in ws[0..4096B) ----
#define WD_SZ 256            // per-direction block
#define XPW 0                // x_proj rows [33][4]
#define CVW 132              // conv_w [4][4]
#define CVB 148              // conv_b [4]
#define DTW 152              // dt_proj_w [4]
#define DTB 156              // dt_proj_b [4]
#define AW  160              // A = -exp(A_log)*log2(e) [4][16]  (pre-scaled for exp2)
#define DW  224              // D [4]
#define G_INPROJ 512         // in_proj [8][2]
#define G_NORMW 528
#define G_OUTP 530           // out_proj [2][4]
#define G_NORMF 538
#define FLG 1000             // 1.0f if inputs/outputs fp32, 0.0f if bf16

// ---- ws byte offsets (~68 MiB) ----
#define PQ_OFF 4096
#define PQ_BYTES ((size_t)BB*2*NC*64*8)            // 8.39 MB  per-chunk (P,Q)
#define SP_OFF (PQ_OFF + PQ_BYTES)
#define SP_BYTES ((size_t)BB*2*NSPAN*64*8)         // 0.52 MB  span tables
#define SG_OFF (SP_OFF + SP_BYTES)
#define SG_BYTES ((size_t)BB*NC*2*64*4*4)          // 16.8 MB  s_t[d] fp32 [cd][t][d]
#define CG_OFF (SG_OFF + SG_BYTES)
#define CG_BYTES ((size_t)BB*NC*2*64*16*2)         // 33.6 MB  C bf16 [cd][t][n]
#define YB_OFF (CG_OFF + CG_BYTES)
#define YB_BYTES ((size_t)BB*NC*64*4*4)            // 8.39 MB  ybase fp32 [g][t][d]

#define LOG2E 1.4426950408889634f

__device__ __forceinline__ float bf2f(unsigned short u){ return __uint_as_float(((unsigned int)u)<<16); }
__device__ __forceinline__ float blo(unsigned int u){ return __uint_as_float(u<<16); }
__device__ __forceinline__ float bhi(unsigned int u){ return __uint_as_float(u & 0xffff0000u); }

// HW packed f32->bf16 (RNE). 1 VALU inst.
__device__ __forceinline__ unsigned int cvtpk(float lo, float hi){
  unsigned int r;
  asm("v_cvt_pk_bf16_f32 %0, %1, %2" : "=v"(r) : "v"(lo), "v"(hi));
  return r;
}
__device__ __forceinline__ unsigned short cvt1(float x){
  return (unsigned short)cvtpk(x, x);
}

__device__ __forceinline__ float siluf(float x){ return x / (1.f + __expf(-x)); }
__device__ __forceinline__ float softplusf_(float x){ return fmaxf(x,0.f) + log1pf(__expf(-fabsf(x))); }

// raw v_exp_f32 (exp2). A is pre-scaled by log2(e) so no extra mul.
__device__ __forceinline__ float exp2fast(float x){
#if __has_builtin(__builtin_amdgcn_exp2f)
  return __builtin_amdgcn_exp2f(x);
#else
  float r; asm("v_exp_f32 %0, %1\ns_nop 0" : "=v"(r) : "v"(x)); return r;
#endif
}

// sum over the 16-lane DPP row (lanes n=0..15 of each d-group).
__device__ __forceinline__ float rowsum16(float x){
  asm("s_nop 1\n\t"
      "v_add_f32_dpp %0, %0, %0 row_ror:1 row_mask:0xf bank_mask:0xf\n\t"
      "s_nop 1\n\t"
      "v_add_f32_dpp %0, %0, %0 row_ror:2 row_mask:0xf bank_mask:0xf\n\t"
      "s_nop 1\n\t"
      "v_add_f32_dpp %0, %0, %0 row_ror:4 row_mask:0xf bank_mask:0xf\n\t"
      "s_nop 1\n\t"
      "v_add_f32_dpp %0, %0, %0 row_ror:8 row_mask:0xf bank_mask:0xf"
      : "+v"(x));
  return x;
}

// wave64 inclusive prefix sum (DPP scan).
__device__ __forceinline__ float wavescan_incl(float x){
  union { float f; int i; } a, t;
  a.f = x;
  t.i = __builtin_amdgcn_update_dpp(0, a.i, 0x111, 0xf, 0xf, true); a.f += t.f; // row_shr:1
  t.i = __builtin_amdgcn_update_dpp(0, a.i, 0x112, 0xf, 0xf, true); a.f += t.f; // row_shr:2
  t.i = __builtin_amdgcn_update_dpp(0, a.i, 0x114, 0xf, 0xf, true); a.f += t.f; // row_shr:4
  t.i = __builtin_amdgcn_update_dpp(0, a.i, 0x118, 0xf, 0xf, true); a.f += t.f; // row_shr:8
  t.i = __builtin_amdgcn_update_dpp(0, a.i, 0x142, 0xa, 0xf, true); a.f += t.f; // row_bcast:15
  t.i = __builtin_amdgcn_update_dpp(0, a.i, 0x143, 0xc, 0xf, true); a.f += t.f; // row_bcast:31
  return a.f;
}
__device__ __forceinline__ float readlane63(float x){
  union { float f; int i; } a; a.f = x;
  return __uint_as_float((unsigned)__builtin_amdgcn_readlane(a.i, 63));
}

__device__ __forceinline__ float ldw(const void* p, int i, int isf){
  return isf ? ((const float*)p)[i] : bf2f(((const unsigned short*)p)[i]);
}
__device__ __forceinline__ float2 hid2(const void* hid, int isf, int b, int t){
  if (isf){
    const float* p = (const float*)hid;
    return make_float2(p[(size_t)b*2*LL + t], p[(size_t)b*2*LL + LL + t]);
  }
  const unsigned short* p = (const unsigned short*)hid;
  return make_float2(bf2f(p[(size_t)b*2*LL + t]), bf2f(p[(size_t)b*2*LL + LL + t]));
}
__device__ __forceinline__ float4 xrow(const void* __restrict__ hid, int isf,
                                       const float* __restrict__ W, int b, int t){
  float2 h = hid2(hid, isf, b, t);
  float ms = rsqrtf(0.5f*(h.x*h.x + h.y*h.y) + 1e-5f);
  float v0 = h.x*ms*W[G_NORMW], v1 = h.y*ms*W[G_NORMW+1];
  float4 x;
  x.x = W[G_INPROJ+0]*v0 + W[G_INPROJ+1]*v1;
  x.y = W[G_INPROJ+2]*v0 + W[G_INPROJ+3]*v1;
  x.z = W[G_INPROJ+4]*v0 + W[G_INPROJ+5]*v1;
  x.w = W[G_INPROJ+6]*v0 + W[G_INPROJ+7]*v1;
  return x;
}

// ---------------- kernel 0: weight prep ----------------
__global__ void k_prep(const void* __restrict__ normw, const void* __restrict__ inpj,
    const void* __restrict__ cwf, const void* __restrict__ cbf,
    const void* __restrict__ xpf, const void* __restrict__ dwf,
    const void* __restrict__ dbf, const void* __restrict__ alf,
    const void* __restrict__ ddf,
    const void* __restrict__ cwb, const void* __restrict__ cbb,
    const void* __restrict__ xpb, const void* __restrict__ dwb,
    const void* __restrict__ dbb, const void* __restrict__ alb,
    const void* __restrict__ ddb,
    const void* __restrict__ outp, const void* __restrict__ nfw,
    float* __restrict__ W)
{
  const int isf = (((const unsigned int*)ddf)[0] == 0x3F800000u) ? 1 : 0;
  int t = threadIdx.x;
  for (int i=t;i<132;i+=256){ W[XPW+i]=ldw(xpf,i,isf); W[WD_SZ+XPW+i]=ldw(xpb,i,isf); }
  for (int i=t;i<16;i+=256){ W[CVW+i]=ldw(cwf,i,isf); W[WD_SZ+CVW+i]=ldw(cwb,i,isf); W[G_INPROJ+i]=ldw(inpj,i,isf); }
  for (int i=t;i<4;i+=256){
    W[CVB+i]=ldw(cbf,i,isf); W[WD_SZ+CVB+i]=ldw(cbb,i,isf);
    W[DTW+i]=ldw(dwf,i,isf); W[WD_SZ+DTW+i]=ldw(dwb,i,isf);
    W[DTB+i]=ldw(dbf,i,isf); W[WD_SZ+DTB+i]=ldw(dbb,i,isf);
    W[DW+i] =ldw(ddf,i,isf); W[WD_SZ+DW+i] =ldw(ddb,i,isf);
  }
  for (int i=t;i<64;i+=256){
    W[AW+i]       = -__expf(ldw(alf,i,isf)) * LOG2E;
    W[WD_SZ+AW+i] = -__expf(ldw(alb,i,isf)) * LOG2E;
  }
  for (int i=t;i<8;i+=256) W[G_OUTP+i]=ldw(outp,i,isf);
  for (int i=t;i<2;i+=256){ W[G_NORMW+i]=ldw(normw,i,isf); W[G_NORMF+i]=ldw(nfw,i,isf); }
  if (t==0) W[FLG] = (float)isf;
}

// ---- per-direction local scan (returns local h). Fully unrolled so all
// LDS accesses become base + compile-time immediate (no per-iter addr math).
template<int DR>
__device__ __forceinline__ float scan_local(const float (* __restrict__ dtPd)[68],
    const float (* __restrict__ dtud)[68],
    const unsigned int (* __restrict__ bcd)[68],
    float (* __restrict__ ySd)[68],
    float Ax, int d, int n)
{
  float h = 0.f;
  #pragma unroll
  for (int j4=0; j4<16; j4++){
    const int t0 = DR ? 60-4*j4 : 4*j4;
    float4  d4 = *(const float4*)&dtPd[d][t0];
    float4  u4 = *(const float4*)&dtud[d][t0];
    uint4   c4 = *(const uint4*)&bcd[n][t0];
    float da[4]={d4.x,d4.y,d4.z,d4.w};
    float ua[4]={u4.x,u4.y,u4.z,u4.w};
    unsigned int ca[4]={c4.x,c4.y,c4.z,c4.w};
    float s[4];
    #pragma unroll
    for (int jr=0; jr<4; jr++){
      const int k  = DR ? 3-jr : jr;         // bwd consumes t descending
      float e = exp2fast(Ax*da[k]);
      h = fmaf(e, h, ua[k]*blo(ca[k]));
      s[k] = rowsum16(h*bhi(ca[k]));
    }
    if (n == 0) *(float4*)&ySd[d][t0] = make_float4(s[0],s[1],s[2],s[3]);
  }
  return h;
}

// ---------------- kernel 1: per-chunk local scan, dir per wave ----------------
__global__ __launch_bounds__(128, 4) void k_chunk2(const void* __restrict__ hid,
    const float* __restrict__ W, float2* __restrict__ PQ,
    float* __restrict__ sG, unsigned int* __restrict__ Cg,
    float4* __restrict__ YB)
{
  // xb (1120B, dead after preamble) overlaps yS (2176B, written during scan)
  __shared__ __align__(16) char smx[2176];
  __shared__ __align__(16) float dtP[2][4][68];            // 2176
  __shared__ __align__(16) float dtuP[2][4][68];           // 2176 fp32 dt*u
  __shared__ __align__(16) unsigned int BCp[2][16][68];    // 8704 (B | C<<16) bf16
  __shared__ __align__(16) float uD[2][256];               // 2048 u*D
  __shared__ float sTot[2][4];
  float4* xb = (float4*)smx;
  float (*yS)[4][68] = (float (*)[4][68])smx;

  const int tid  = threadIdx.x;
  const int wid  = tid >> 6;         // 0=fwd wave, 1=bwd wave
  const int lane = tid & 63;
  const int gid  = blockIdx.x;       // (b,c)
  const int c    = gid & (NC-1);
  const int b    = gid >> 9;
  const int isf  = (int)W[FLG];
  const size_t cd = (size_t)gid*2 + wid;

  // xb staging split over ALL 128 threads: xb[e] <-> t = c*64 - 3 + e, e in [0,70)
  if (tid < 70){
    int t2 = c*64 - 3 + tid;
    float4 v = make_float4(0.f,0.f,0.f,0.f);
    if (t2 >= 0 && t2 < LL) v = xrow(hid, isf, W, b, t2);
    xb[tid] = v;
  }
  __syncthreads();
  {
    const float* Wd = W + wid*WD_SZ;
    float4 a0,a1,a2,a3;
    if (wid == 0){ a0=xb[lane];   a1=xb[lane+1]; a2=xb[lane+2]; a3=xb[lane+3]; }
    else         { a0=xb[lane+6]; a1=xb[lane+5]; a2=xb[lane+4]; a3=xb[lane+3]; }
    float u[4];
    u[0] = siluf(Wd[CVB+0] + Wd[CVW+ 0]*a0.x + Wd[CVW+ 1]*a1.x + Wd[CVW+ 2]*a2.x + Wd[CVW+ 3]*a3.x);
    u[1] = siluf(Wd[CVB+1] + Wd[CVW+ 4]*a0.y + Wd[CVW+ 5]*a1.y + Wd[CVW+ 6]*a2.y + Wd[CVW+ 7]*a3.y);
    u[2] = siluf(Wd[CVB+2] + Wd[CVW+ 8]*a0.z + Wd[CVW+ 9]*a1.z + Wd[CVW+10]*a2.z + Wd[CVW+11]*a3.z);
    u[3] = siluf(Wd[CVB+3] + Wd[CVW+12]*a0.w + Wd[CVW+13]*a1.w + Wd[CVW+14]*a2.w + Wd[CVW+15]*a3.w);
    float dtr = Wd[XPW+0]*u[0] + Wd[XPW+1]*u[1] + Wd[XPW+2]*u[2] + Wd[XPW+3]*u[3];
    float4 ud4;
    #pragma unroll
    for (int d2=0; d2<4; d2++){
      float dt = softplusf_(fmaf(Wd[DTW+d2], dtr, Wd[DTB+d2]));
      dtP[wid][d2][lane]  = dt;
      dtuP[wid][d2][lane] = dt*u[d2];
      ((float*)&ud4)[d2] = u[d2]*Wd[DW+d2];
    }
    *(float4*)&uD[wid][lane*4] = ud4;
    float Cl[16];
    #pragma unroll
    for (int n=0; n<16; n++){
      float Bn = Wd[XPW+(1+n)*4+0]*u[0] + Wd[XPW+(1+n)*4+1]*u[1]
               + Wd[XPW+(1+n)*4+2]*u[2] + Wd[XPW+(1+n)*4+3]*u[3];
      float Cn = Wd[XPW+(17+n)*4+0]*u[0] + Wd[XPW+(17+n)*4+1]*u[1]
               + Wd[XPW+(17+n)*4+2]*u[2] + Wd[XPW+(17+n)*4+3]*u[3];
      BCp[wid][n][lane] = cvtpk(Bn, Cn);
      Cl[n] = Cn;
    }
    // store C row for k_final: [cd][t][n] bf16, 32B per lane
    unsigned int cp[8];
    #pragma unroll
    for (int q=0;q<8;q++) cp[q] = cvtpk(Cl[2*q], Cl[2*q+1]);
    uint4* cgw = (uint4*)(Cg + cd*512);
    cgw[lane*2+0] = *(uint4*)&cp[0];
    cgw[lane*2+1] = *(uint4*)&cp[4];
  }
  __syncthreads();   // also protects xb->yS union

  // cumulative dt (prefix-incl for fwd, suffix-incl for bwd), lane = t
  {
    float sv[4], tt[4];
    #pragma unroll
    for (int d2=0; d2<4; d2++){
      float v = dtP[wid][d2][lane];
      float x = wavescan_incl(v);
      float tot = readlane63(x);
      if (wid) x = tot - x + v;        // suffix-inclusive
      sv[d2] = x; tt[d2] = tot;
    }
    *(float4*)(sG + cd*256 + lane*4) = make_float4(sv[0],sv[1],sv[2],sv[3]);
    if (lane == 0){ sTot[wid][0]=tt[0]; sTot[wid][1]=tt[1]; sTot[wid][2]=tt[2]; sTot[wid][3]=tt[3]; }
  }

  const int d = lane>>4, n = lane&15;
  const float Ax = W[wid*WD_SZ + AW + d*16 + n];
  float h;
  size_t idx;
  if (wid == 0){
    h   = scan_local<0>(dtP[0], dtuP[0], BCp[0], yS[0], Ax, d, n);
    idx = ((size_t)(b*2+0)*NC + c);
  } else {
    h   = scan_local<1>(dtP[1], dtuP[1], BCp[1], yS[1], Ax, d, n);
    idx = ((size_t)(b*2+1)*NC + (NC-1-c));
  }
  float P = exp2fast(Ax * sTot[wid][d]);   // = prod of per-step decays
  PQ[idx*64 + lane] = make_float2(P, h);
  __syncthreads();

  // ybase = y_loc_f + y_loc_b + uD_f + uD_b   (fp32, [t][d] float4)
  if (wid == 0){
    float4 v;
    v.x = yS[0][0][lane] + yS[1][0][lane] + uD[0][lane*4+0] + uD[1][lane*4+0];
    v.y = yS[0][1][lane] + yS[1][1][lane] + uD[0][lane*4+1] + uD[1][lane*4+1];
    v.z = yS[0][2][lane] + yS[1][2][lane] + uD[0][lane*4+2] + uD[1][lane*4+2];
    v.w = yS[0][3][lane] + yS[1][3][lane] + uD[0][lane*4+3] + uD[1][lane*4+3];
    YB[(size_t)gid*64 + lane] = v;
  }
}

// ---------------- kernel 2: span tables (16-chunk composition) ----------------
__global__ __launch_bounds__(64) void k_spans(const float2* __restrict__ PQ,
                                              float2* __restrict__ SP)
{
  const int blk  = blockIdx.x;           // bd*NSPAN + span
  const int lane = threadIdx.x;
  const int bd   = blk >> 5, span = blk & (NSPAN-1);
  const float2* p = PQ + ((size_t)bd*NC + span*SPLEN)*64 + lane;
  float2 v[SPLEN];
  #pragma unroll
  for (int k=0;k<SPLEN;k++) v[k] = p[k*64];
  float A = 1.f, Bc = 0.f;
  #pragma unroll
  for (int k=0;k<SPLEN;k++){ A *= v[k].x; Bc = fmaf(v[k].x, Bc, v[k].y); }
  SP[((size_t)bd*NSPAN + span)*64 + lane] = make_float2(A,Bc);
}

// compose entry state for (bd, position p): s full spans + wn chunk entries
__device__ __forceinline__ float compose_h0(const float2* __restrict__ PQ,
    const float2* __restrict__ SP, int bd, int p, int lane)
{
  const int s  = p >> 4, wn = p & 15;
  const float2* SPb = SP + (size_t)bd*NSPAN*64 + lane;
  const float2* PQb = PQ + ((size_t)bd*NC + (p & ~15))*64 + lane;
  float h = 0.f;
  #pragma unroll
  for (int jg=0; jg<4; jg++){
    if (jg*8 < s){                         // wave-uniform group skip
      float2 v[8];
      #pragma unroll
      for (int j=0;j<8;j++){ int jj = jg*8+j; v[j] = SPb[(size_t)(jj<s?jj:0)*64]; }
      #pragma unroll
      for (int j=0;j<8;j++){ int jj = jg*8+j; if (jj<s) h = fmaf(v[j].x, h, v[j].y); }
    }
  }
  #pragma unroll
  for (int jg=0; jg<2; jg++){
    if (jg*8 < wn){
      float2 v[8];
      #pragma unroll
      for (int j=0;j<8;j++){ int jj = jg*8+j; v[j] = PQb[(size_t)(jj<wn?jj:0)*64]; }
      #pragma unroll
      for (int j=0;j<8;j++){ int jj = jg*8+j; if (jj<wn) h = fmaf(v[j].x, h, v[j].y); }
    }
  }
  return h;
}

// ---------------- kernel 3: one wave per chunk, both dirs, full epilogue ----------------
// 2048 blocks x 256 thr (4 independent waves). Each wave: compose its own
// hF/hB entry states (PQ+SP are L2-resident), publish to a private 512B LDS
// slice, then correction = sum_n exp2(A*s)*C*h0 for both dirs + epilogue.
// (256,4): measured-best operating point — (256,6) thrashes cache, (256,8)
// forces VGPR<=64 and spills catastrophically (R10/R12).
__global__ __launch_bounds__(256, 4) void k_final(const void* __restrict__ hid,
    const float* __restrict__ W, const float2* __restrict__ PQ,
    const float2* __restrict__ SP, const float* __restrict__ sG,
    const unsigned int* __restrict__ Cg, const float4* __restrict__ YB,
    void* __restrict__ out)
{
  __shared__ float h0sF[4][64];
  __shared__ float h0sB[4][64];
  const int lane = threadIdx.x & 63;
  const int w    = threadIdx.x >> 6;
  const int unit = blockIdx.x*4 + w;       // b*NC + c
  const int b    = unit >> 9;
  const int c    = unit & (NC-1);
  const int isf  = (int)W[FLG];

  // issue all data loads first (in flight during the compose chains)
  const size_t cdF = (size_t)unit*2, cdB = cdF + 1;
  float4 sF = *(const float4*)(sG + cdF*256 + lane*4);
  float4 sB = *(const float4*)(sG + cdB*256 + lane*4);
  uint4 cFa = ((const uint4*)(Cg + cdF*512))[lane*2+0];
  uint4 cFb = ((const uint4*)(Cg + cdF*512))[lane*2+1];
  uint4 cBa = ((const uint4*)(Cg + cdB*512))[lane*2+0];
  uint4 cBb = ((const uint4*)(Cg + cdB*512))[lane*2+1];
  float4 yb = YB[(size_t)unit*64 + lane];
  const int tg = c*64 + lane;
  float2 r = hid2(hid, isf, b, tg);

  // compose entry states (lane = dn), publish to this wave's LDS slice
  float hF = compose_h0(PQ, SP, b*2+0, c,      lane);
  float hB = compose_h0(PQ, SP, b*2+1, NC-1-c, lane);
  h0sF[w][lane] = hF;
  h0sB[w][lane] = hB;      // same-wave write->read, lgkmcnt ordering

  // unpack C (16 bf16 per dir for this lane's t)
  float cfF[16], cfB[16];
  cfF[ 0]=blo(cFa.x); cfF[ 1]=bhi(cFa.x); cfF[ 2]=blo(cFa.y); cfF[ 3]=bhi(cFa.y);
  cfF[ 4]=blo(cFa.z); cfF[ 5]=bhi(cFa.z); cfF[ 6]=blo(cFa.w); cfF[ 7]=bhi(cFa.w);
  cfF[ 8]=blo(cFb.x); cfF[ 9]=bhi(cFb.x); cfF[10]=blo(cFb.y); cfF[11]=bhi(cFb.y);
  cfF[12]=blo(cFb.z); cfF[13]=bhi(cFb.z); cfF[14]=blo(cFb.w); cfF[15]=bhi(cFb.w);
  cfB[ 0]=blo(cBa.x); cfB[ 1]=bhi(cBa.x); cfB[ 2]=blo(cBa.y); cfB[ 3]=bhi(cBa.y);
  cfB[ 4]=blo(cBa.z); cfB[ 5]=bhi(cBa.z); cfB[ 6]=blo(cBa.w); cfB[ 7]=bhi(cBa.w);
  cfB[ 8]=blo(cBb.x); cfB[ 9]=bhi(cBb.x); cfB[10]=blo(cBb.y); cfB[11]=bhi(cBb.y);
  cfB[12]=blo(cBb.z); cfB[13]=bhi(cBb.z); cfB[14]=blo(cBb.w); cfB[15]=bhi(cBb.w);

  // correction: both dirs. A via uniform (scalar) loads from W.
  float4 corr;
  #pragma unroll
  for (int d2=0; d2<4; d2++){
    float sdF = ((const float*)&sF)[d2];
    float sdB = ((const float*)&sB)[d2];
    float acc = 0.f;
    #pragma unroll
    for (int q=0;q<4;q++){
      float4 aF = *(const float4*)(W + AW + d2*16 + q*4);
      float4 aB = *(const float4*)(W + WD_SZ + AW + d2*16 + q*4);
      float4 hF4 = *(const float4*)&h0sF[w][d2*16 + q*4];
      float4 hB4 = *(const float4*)&h0sB[w][d2*16 + q*4];
      acc = fmaf(exp2fast(aF.x*sdF), cfF[q*4+0]*hF4.x, acc);
      acc = fmaf(exp2fast(aF.y*sdF), cfF[q*4+1]*hF4.y, acc);
      acc = fmaf(exp2fast(aF.z*sdF), cfF[q*4+2]*hF4.z, acc);
      acc = fmaf(exp2fast(aF.w*sdF), cfF[q*4+3]*hF4.w, acc);
      acc = fmaf(exp2fast(aB.x*sdB), cfB[q*4+0]*hB4.x, acc);
      acc = fmaf(exp2fast(aB.y*sdB), cfB[q*4+1]*hB4.y, acc);
      acc = fmaf(exp2fast(aB.z*sdB), cfB[q*4+2]*hB4.z, acc);
      acc = fmaf(exp2fast(aB.w*sdB), cfB[q*4+3]*hB4.w, acc);
    }
    ((float*)&corr)[d2] = acc;
  }

  // epilogue (lane = t)
  {
    float ms0 = rsqrtf(0.5f*(r.x*r.x + r.y*r.y) + 1e-5f);
    float v0 = r.x*ms0*W[G_NORMW], v1 = r.y*ms0*W[G_NORMW+1];
    float z0 = siluf(W[G_INPROJ+ 8]*v0 + W[G_INPROJ+ 9]*v1);
    float z1 = siluf(W[G_INPROJ+10]*v0 + W[G_INPROJ+11]*v1);
    float z2 = siluf(W[G_INPROJ+12]*v0 + W[G_INPROJ+13]*v1);
    float z3 = siluf(W[G_INPROJ+14]*v0 + W[G_INPROJ+15]*v1);

    float y0 = (yb.x + corr.x) * z0;
    float y1 = (yb.y + corr.y) * z1;
    float y2 = (yb.z + corr.z) * z2;
    float y3 = (yb.w + corr.w) * z3;
    float o0 = W[G_OUTP+0]*y0 + W[G_OUTP+1]*y1 + W[G_OUTP+2]*y2 + W[G_OUTP+3]*y3;
    float o1 = W[G_OUTP+4]*y0 + W[G_OUTP+5]*y1 + W[G_OUTP+6]*y2 + W[G_OUTP+7]*y3;
    o0 += r.x;
    o1 += r.y;
    float ms = rsqrtf(0.5f*(o0*o0 + o1*o1) + 1e-5f);
    float e0 = o0*ms*W[G_NORMF], e1 = o1*ms*W[G_NORMF+1];
    size_t i0 = (size_t)b*2*LL + tg, i1 = i0 + LL;
    if (isf){
      ((float*)out)[i0] = e0;
      ((float*)out)[i1] = e1;
    } else {
      ((unsigned short*)out)[i0] = cvt1(e0);
      ((unsigned short*)out)[i1] = cvt1(e1);
    }
  }
}

extern "C" void kernel_launch(void* const* d_in, const int* in_sizes, int n_in,
                              void* d_out, int out_size, void* d_ws, size_t ws_size,
                              hipStream_t stream)
{
  (void)in_sizes; (void)n_in; (void)out_size; (void)ws_size;
  const void* hid   = d_in[0];
  const void* normw = d_in[1];
  const void* inpj  = d_in[2];
  const void* cwf   = d_in[3];
  const void* cbf   = d_in[4];
  const void* xpf   = d_in[5];
  const void* dwf   = d_in[6];
  const void* dbf   = d_in[7];
  const void* alf   = d_in[8];
  const void* ddf   = d_in[9];
  const void* cwb   = d_in[10];
  const void* cbb   = d_in[11];
  const void* xpb   = d_in[12];
  const void* dwb   = d_in[13];
  const void* dbb   = d_in[14];
  const void* alb   = d_in[15];
  const void* ddb   = d_in[16];
  const void* outp  = d_in[17];
  const void* nfw   = d_in[18];

  float* W            = (float*)d_ws;
  float2* PQ          = (float2*)((char*)d_ws + PQ_OFF);
  float2* SPt         = (float2*)((char*)d_ws + SP_OFF);
  float* sG           = (float*)((char*)d_ws + SG_OFF);
  unsigned int* Cg    = (unsigned int*)((char*)d_ws + CG_OFF);
  float4* YB          = (float4*)((char*)d_ws + YB_OFF);

  k_prep<<<1,256,0,stream>>>(normw, inpj, cwf, cbf, xpf, dwf, dbf, alf, ddf,
                             cwb, cbb, xpb, dwb, dbb, alb, ddb, outp, nfw, W);
  k_chunk2<<<BB*NC, 128, 0, stream>>>(hid, W, PQ, sG, Cg, YB);
  k_spans<<<BB*2*NSPAN, 64, 0, stream>>>(PQ, SPt);
  k_final<<<BB*NC/4, 256, 0, stream>>>(hid, W, PQ, SPt, sG, Cg, YB, d_out);
}